// Round 15
// baseline (338.133 us; speedup 1.0000x reference)
//
#include <hip/hip_runtime.h>

#define NUM_USER 100000
#define NUM_ITEM 50000
#define NNODE 150000
#define EMBED_DIM 64
#define NNZ_CNT 5000000
#define BATCH 4096

#define BROWS 256
#define NBUCK ((NNODE + BROWS - 1) / BROWS)       // 586
#define NBLK 512
#define CHUNK4 9768                                // per-block edges, multiple of 8
#define COLMASK 0x3FFFF                            // 18 bits, col < 262144
#define VSHIFT 18                                  // val14 in bits 18..31 of packed csr
#define VSCALE (1.0f / 16384.0f)

__device__ __forceinline__ unsigned short f2bf(float f) {
    unsigned b = __float_as_uint(f);
    return (unsigned short)((b + 0x7FFFu + ((b >> 16) & 1u)) >> 16);  // RNE
}
__device__ __forceinline__ float bf2f(unsigned short u) {
    return __uint_as_float((unsigned)u << 16);
}

// ---------- CSR build: per-block hist -> 2-level scan -> scatter -> bucket sort ----------

// Per-block LDS histogram; 4 consecutive edges/thread (int4 loads, 4-deep ILP).
__global__ __launch_bounds__(1024) void bhist_local(const int* __restrict__ row,
                                                    int* __restrict__ histT) {
    __shared__ int lh[NBUCK];
    for (int i = threadIdx.x; i < NBUCK; i += blockDim.x) lh[i] = 0;
    __syncthreads();
    const int lo = blockIdx.x * CHUNK4;
    const int hi = min(lo + CHUNK4, NNZ_CNT);
    for (int base = lo; base < hi; base += 4096) {
        const int e0 = base + (int)threadIdx.x * 4;
        if (e0 + 4 <= hi) {
            const int4 r4 = *(const int4*)&row[e0];
            atomicAdd(&lh[r4.x >> 8], 1);
            atomicAdd(&lh[r4.y >> 8], 1);
            atomicAdd(&lh[r4.z >> 8], 1);
            atomicAdd(&lh[r4.w >> 8], 1);
        } else if (e0 < hi) {
            for (int e = e0; e < hi; ++e) atomicAdd(&lh[row[e] >> 8], 1);
        }
    }
    __syncthreads();
    for (int i = threadIdx.x; i < NBUCK; i += blockDim.x)
        histT[i * NBLK + blockIdx.x] = lh[i];
}

__global__ __launch_bounds__(512) void scanA(int* __restrict__ histT,
                                             int* __restrict__ btot) {
    const int g = (int)((blockIdx.x * blockDim.x + threadIdx.x) >> 6);
    const int lane = threadIdx.x & 63;
    if (g >= NBUCK) return;
    const int base = g * NBLK + lane * 8;
    int v[8];
    int s = 0;
    #pragma unroll
    for (int u = 0; u < 8; ++u) { v[u] = histT[base + u]; s += v[u]; }
    int pre = s;
    #pragma unroll
    for (int off = 1; off < 64; off <<= 1) {
        int t = __shfl_up(pre, off, 64);
        if (lane >= off) pre += t;
    }
    int excl = pre - s;
    #pragma unroll
    for (int u = 0; u < 8; ++u) { const int w = v[u]; histT[base + u] = excl; excl += w; }
    if (lane == 63) btot[g] = pre;
}

__global__ __launch_bounds__(1024) void scanB(const int* __restrict__ btot,
                                              int* __restrict__ bptr) {
    __shared__ int sums[1024];
    const int t = threadIdx.x;
    const int s = (t < NBUCK) ? btot[t] : 0;
    sums[t] = s;
    __syncthreads();
    for (int off = 1; off < 1024; off <<= 1) {
        int v = (t >= off) ? sums[t - off] : 0;
        __syncthreads();
        sums[t] += v;
        __syncthreads();
    }
    if (t < NBUCK) bptr[t] = sums[t] - s;
    if (t == 0) bptr[NBUCK] = NNZ_CNT;
}

// Scatter edges into bucket-grouped order; 4 consecutive edges/thread.
// Emits the FINAL packed CSR word (val14<<18 | col18) + separate row-local byte.
__global__ __launch_bounds__(1024) void bscatter2(const float* __restrict__ vals,
                                                  const int* __restrict__ row,
                                                  const int* __restrict__ col,
                                                  const int* __restrict__ histT,
                                                  const int* __restrict__ bptr,
                                                  unsigned* __restrict__ grouped4,
                                                  unsigned char* __restrict__ rlb) {
    __shared__ int lh[NBUCK];
    const int b = blockIdx.x;
    for (int i = threadIdx.x; i < NBUCK; i += blockDim.x)
        lh[i] = bptr[i] + histT[i * NBLK + b];
    __syncthreads();
    const int lo = b * CHUNK4;
    const int hi = min(lo + CHUNK4, NNZ_CNT);
    auto pack = [](float v, int c) -> unsigned {
        unsigned u = (unsigned)(v * 16384.0f + 0.5f);
        if (u > 16383u) u = 16383u;
        return (u << VSHIFT) | ((unsigned)c & COLMASK);
    };
    for (int base = lo; base < hi; base += 4096) {
        const int e0 = base + (int)threadIdx.x * 4;
        if (e0 + 4 <= hi) {
            const int4   r4 = *(const int4*)&row[e0];
            const int4   c4 = *(const int4*)&col[e0];
            const float4 v4 = *(const float4*)&vals[e0];
            const int p0 = atomicAdd(&lh[r4.x >> 8], 1);
            const int p1 = atomicAdd(&lh[r4.y >> 8], 1);
            const int p2 = atomicAdd(&lh[r4.z >> 8], 1);
            const int p3 = atomicAdd(&lh[r4.w >> 8], 1);
            grouped4[p0] = pack(v4.x, c4.x); rlb[p0] = (unsigned char)(r4.x & 255);
            grouped4[p1] = pack(v4.y, c4.y); rlb[p1] = (unsigned char)(r4.y & 255);
            grouped4[p2] = pack(v4.z, c4.z); rlb[p2] = (unsigned char)(r4.z & 255);
            grouped4[p3] = pack(v4.w, c4.w); rlb[p3] = (unsigned char)(r4.w & 255);
        } else if (e0 < hi) {
            for (int e = e0; e < hi; ++e) {
                const int r = row[e];
                const int pos = atomicAdd(&lh[r >> 8], 1);
                grouped4[pos] = pack(vals[e], col[e]);
                rlb[pos] = (unsigned char)(r & 255);
            }
        }
    }
}

// One WG per bucket: hist from the 1-byte rl stream (5 MB total), then copy the
// already-packed 4B words into row-sorted CSR. 4-deep strided ILP.
__global__ __launch_bounds__(512) void bucket_sort(const int* __restrict__ bptr,
                                                   const unsigned* __restrict__ grouped4,
                                                   const unsigned char* __restrict__ rlb,
                                                   unsigned* __restrict__ csr,
                                                   int* __restrict__ row_ptr) {
    __shared__ int lh[BROWS];
    __shared__ int lbase[BROWS];
    const int b = blockIdx.x;
    const int bstart = bptr[b];
    const int bend   = bptr[b + 1];
    if (threadIdx.x < BROWS) lh[threadIdx.x] = 0;
    __syncthreads();
    int e = bstart + (int)threadIdx.x;
    for (; e + 1536 < bend; e += 2048) {
        const int r0 = rlb[e];
        const int r1 = rlb[e + 512];
        const int r2 = rlb[e + 1024];
        const int r3 = rlb[e + 1536];
        atomicAdd(&lh[r0], 1);
        atomicAdd(&lh[r1], 1);
        atomicAdd(&lh[r2], 1);
        atomicAdd(&lh[r3], 1);
    }
    for (; e < bend; e += 512)
        atomicAdd(&lh[rlb[e]], 1);
    __syncthreads();
    if (threadIdx.x == 0) {
        int run = 0;
        for (int i = 0; i < BROWS; ++i) { const int c = lh[i]; lbase[i] = run; run += c; }
    }
    __syncthreads();
    const int node = b * BROWS + (int)threadIdx.x;
    if (threadIdx.x < BROWS && node < NNODE) row_ptr[node] = bstart + lbase[threadIdx.x];
    if (threadIdx.x < BROWS) lh[threadIdx.x] = lbase[threadIdx.x];
    __syncthreads();
    e = bstart + (int)threadIdx.x;
    for (; e + 1536 < bend; e += 2048) {
        const int r0 = rlb[e];
        const int r1 = rlb[e + 512];
        const int r2 = rlb[e + 1024];
        const int r3 = rlb[e + 1536];
        const unsigned w0 = grouped4[e];
        const unsigned w1 = grouped4[e + 512];
        const unsigned w2 = grouped4[e + 1024];
        const unsigned w3 = grouped4[e + 1536];
        csr[bstart + atomicAdd(&lh[r0], 1)] = w0;
        csr[bstart + atomicAdd(&lh[r1], 1)] = w1;
        csr[bstart + atomicAdd(&lh[r2], 1)] = w2;
        csr[bstart + atomicAdd(&lh[r3], 1)] = w3;
    }
    for (; e < bend; e += 512) {
        const int rl = rlb[e];
        const unsigned w = grouped4[e];
        csr[bstart + atomicAdd(&lh[rl], 1)] = w;
    }
}

__global__ void fix_tail(int* __restrict__ row_ptr) {
    row_ptr[NNODE] = NNZ_CNT;
}

// ---------- table concat -> bf16 ----------

__global__ void to_bf16(const float4* __restrict__ ut, const float4* __restrict__ it,
                        ushort4* __restrict__ xbf) {
    const int nu4 = NUM_USER * EMBED_DIM / 4;
    const int nt4 = NNODE * EMBED_DIM / 4;
    int i = blockIdx.x * blockDim.x + threadIdx.x;
    const int stride = gridDim.x * blockDim.x;
    for (; i < nt4; i += stride) {
        const float4 v = (i < nu4) ? ut[i] : it[i - nu4];
        ushort4 o;
        o.x = f2bf(v.x); o.y = f2bf(v.y); o.z = f2bf(v.z); o.w = f2bf(v.w);
        xbf[i] = o;
    }
}

// ---------- pull-mode SpMM (bf16 in / bf16 out), packed 4B CSR, pair-gather ----------
// r14-measured form (LDS_Block_Size==0): one wave per row; half=lane>>5 picks
// the edge of a pair via a cndmask of two NAMED scalars; one dword gather
// serves 2 bf16 channels; cross-half combine via shfl_xor(32).

__global__ __launch_bounds__(256) void spmm_pull(const int* __restrict__ row_ptr,
                          const unsigned* __restrict__ csr,
                          const unsigned short* __restrict__ x,
                          unsigned short* __restrict__ y) {
    const int wave = (int)((blockIdx.x * blockDim.x + threadIdx.x) >> 6);
    const int lane = threadIdx.x & 63;
    if (wave >= NNODE) return;
    const int half = lane >> 5;
    const size_t c4off = (size_t)(lane & 31) * 4;   // byte offset of the dword pair
    const int start = __builtin_amdgcn_readfirstlane(row_ptr[wave]);
    const int end   = __builtin_amdgcn_readfirstlane(row_ptr[wave + 1]);
    float ax = 0.f, ay = 0.f;
    int j = start;
    for (; j + 16 <= end; j += 16) {
        #pragma unroll
        for (int p = 0; p < 8; ++p) {
            unsigned e0, e1;
            __builtin_memcpy(&e0, &csr[j + 2 * p], 4);      // s_load, const offset
            __builtin_memcpy(&e1, &csr[j + 2 * p + 1], 4);  // s_load, const offset
            const unsigned e = half ? e1 : e0;              // cndmask of 2 scalars
            const unsigned w = *(const unsigned*)((const char*)x +
                                 (size_t)(e & COLMASK) * 128 + c4off);
            const float v = (float)(e >> VSHIFT);
            ax += v * __uint_as_float(w << 16);
            ay += v * __uint_as_float(w & 0xFFFF0000u);
        }
    }
    const int rem = end - j;
    if (rem > 8) {                                  // masked 8-pair tail (covers 16)
        #pragma unroll
        for (int p = 0; p < 8; ++p) {
            const int j0 = j + 2 * p + half;
            const int idx = (j0 < end) ? j0 : end - 1;
            unsigned e; __builtin_memcpy(&e, &csr[idx], 4);
            const float v = (j0 < end) ? (float)(e >> VSHIFT) : 0.f;
            const unsigned w = *(const unsigned*)((const char*)x +
                                 (size_t)(e & COLMASK) * 128 + c4off);
            ax += v * __uint_as_float(w << 16);
            ay += v * __uint_as_float(w & 0xFFFF0000u);
        }
    } else if (rem > 0) {                           // masked 4-pair tail (covers 8)
        #pragma unroll
        for (int p = 0; p < 4; ++p) {
            const int j0 = j + 2 * p + half;
            const int idx = (j0 < end) ? j0 : end - 1;
            unsigned e; __builtin_memcpy(&e, &csr[idx], 4);
            const float v = (j0 < end) ? (float)(e >> VSHIFT) : 0.f;
            const unsigned w = *(const unsigned*)((const char*)x +
                                 (size_t)(e & COLMASK) * 128 + c4off);
            ax += v * __uint_as_float(w << 16);
            ay += v * __uint_as_float(w & 0xFFFF0000u);
        }
    }
    ax += __shfl_xor(ax, 32, 64);
    ay += __shfl_xor(ay, 32, 64);
    if (half == 0) {
        const unsigned lo = f2bf(ax * VSCALE);
        const unsigned hi = f2bf(ay * VSCALE);
        ((unsigned*)y)[(size_t)wave * 32 + (lane & 31)] = (hi << 16) | lo; // coalesced
    }
}

// Layer-3 restricted pull for the 8192 batch rows only (r11-proven 16-deep form).
__global__ __launch_bounds__(256) void batch_pull(const int* __restrict__ row_ptr,
                           const unsigned* __restrict__ csr,
                           const unsigned short* __restrict__ x,
                           const int* __restrict__ users,
                           const int* __restrict__ items,
                           float* __restrict__ uacc,
                           float* __restrict__ iacc) {
    const int g = (int)((blockIdx.x * blockDim.x + threadIdx.x) >> 6);
    const int lane = threadIdx.x & 63;
    if (g >= 2 * BATCH) return;
    const bool is_item = g >= BATCH;
    const int b = is_item ? g - BATCH : g;
    const int node = is_item ? items[b] + NUM_USER : users[b];
    const int start = __builtin_amdgcn_readfirstlane(row_ptr[node]);
    const int end   = __builtin_amdgcn_readfirstlane(row_ptr[node + 1]);
    float acc = 0.f;
    int j = start;
    for (; j + 16 <= end; j += 16) {
        unsigned ee[16]; float xv[16];
        #pragma unroll
        for (int u = 0; u < 16; ++u) {
            __builtin_memcpy(&ee[u], &csr[j + u], 4);
            xv[u] = bf2f(x[(size_t)(ee[u] & COLMASK) * EMBED_DIM + lane]);
        }
        #pragma unroll
        for (int u = 0; u < 16; ++u) acc += (float)(ee[u] >> VSHIFT) * xv[u];
    }
    const int rem = end - j;
    if (rem > 8) {
        float vv[16], xv[16];
        #pragma unroll
        for (int u = 0; u < 16; ++u) {
            const int jj = j + u;
            const int idx = (jj < end) ? jj : end - 1;
            unsigned e; __builtin_memcpy(&e, &csr[idx], 4);
            vv[u] = (jj < end) ? (float)(e >> VSHIFT) : 0.f;
            xv[u] = bf2f(x[(size_t)(e & COLMASK) * EMBED_DIM + lane]);
        }
        #pragma unroll
        for (int u = 0; u < 16; ++u) acc += vv[u] * xv[u];
    } else if (rem > 0) {
        float vv[8], xv[8];
        #pragma unroll
        for (int u = 0; u < 8; ++u) {
            const int jj = j + u;
            const int idx = (jj < end) ? jj : end - 1;
            unsigned e; __builtin_memcpy(&e, &csr[idx], 4);
            vv[u] = (jj < end) ? (float)(e >> VSHIFT) : 0.f;
            xv[u] = bf2f(x[(size_t)(e & COLMASK) * EMBED_DIM + lane]);
        }
        #pragma unroll
        for (int u = 0; u < 8; ++u) acc += vv[u] * xv[u];
    }
    float* dst = is_item ? iacc : uacc;
    dst[(size_t)b * EMBED_DIM + lane] += acc * VSCALE;
}

// ---------- accumulators / scoring ----------

__global__ void init_acc(const float* __restrict__ user_table,
                         const float* __restrict__ item_table,
                         const int* __restrict__ users,
                         const int* __restrict__ items,
                         float* __restrict__ uacc,
                         float* __restrict__ iacc) {
    const int tid = blockIdx.x * blockDim.x + threadIdx.x;
    const int b = tid >> 6;
    const int k = tid & 63;
    uacc[tid] = user_table[(size_t)users[b] * EMBED_DIM + k];
    iacc[tid] = item_table[(size_t)items[b] * EMBED_DIM + k];
}

__global__ void gather_add(const unsigned short* __restrict__ src,
                           const int* __restrict__ users,
                           const int* __restrict__ items,
                           float* __restrict__ uacc,
                           float* __restrict__ iacc) {
    const int tid = blockIdx.x * blockDim.x + threadIdx.x;
    const int b = tid >> 6;
    const int k = tid & 63;
    uacc[tid] += bf2f(src[(size_t)users[b] * EMBED_DIM + k]);
    iacc[tid] += bf2f(src[((size_t)items[b] + NUM_USER) * EMBED_DIM + k]);
}

__global__ void score_kernel(const float* __restrict__ uacc,
                             const float* __restrict__ iacc,
                             float* __restrict__ out) {
    const int tid = blockIdx.x * blockDim.x + threadIdx.x;
    const int b = tid >> 6;
    const int k = tid & 63;
    float p = uacc[tid] * iacc[tid];
    #pragma unroll
    for (int off = 32; off > 0; off >>= 1) p += __shfl_down(p, off, 64);
    if (k == 0) out[b] = p * (1.0f / 16.0f);
}

// ---------- launch ----------

extern "C" void kernel_launch(void* const* d_in, const int* in_sizes, int n_in,
                              void* d_out, int out_size, void* d_ws, size_t ws_size,
                              hipStream_t stream) {
    const float* vals       = (const float*)d_in[0];
    const float* user_table = (const float*)d_in[1];
    const float* item_table = (const float*)d_in[2];
    const int*   row        = (const int*)d_in[3];
    const int*   col        = (const int*)d_in[4];
    const int*   users      = (const int*)d_in[5];
    const int*   items      = (const int*)d_in[6];
    float* out = (float*)d_out;

    char* ws = (char*)d_ws;
    size_t off = 0;
    auto alloc = [&](size_t bytes) { char* p = ws + off; off += (bytes + 255) & ~(size_t)255; return p; };
    const size_t NBH = (size_t)NNODE * EMBED_DIM * sizeof(unsigned short); // 19.2 MB
    unsigned short* xbf  = (unsigned short*)alloc(NBH);
    unsigned short* bufA = (unsigned short*)alloc(NBH);
    unsigned* grouped4 = (unsigned*)alloc((size_t)NNZ_CNT * sizeof(unsigned)); // 20 MB (bufB aliases)
    unsigned char* rlb = (unsigned char*)alloc((size_t)NNZ_CNT);               // 5 MB
    unsigned* csr  = (unsigned*)alloc((size_t)NNZ_CNT * sizeof(unsigned));     // 20 MB packed
    int*   row_ptr = (int*)alloc((size_t)(NNODE + 1) * sizeof(int));
    int*   bptr    = (int*)alloc((size_t)(NBUCK + 1) * sizeof(int));
    int*   btot    = (int*)alloc((size_t)NBUCK * sizeof(int));
    int*   histT   = (int*)alloc((size_t)NBUCK * NBLK * sizeof(int));   // 1.2 MB
    float* uacc    = (float*)alloc((size_t)BATCH * EMBED_DIM * sizeof(float));
    float* iacc    = (float*)alloc((size_t)BATCH * EMBED_DIM * sizeof(float));

    // CSR build
    bhist_local<<<NBLK, 1024, 0, stream>>>(row, histT);
    scanA<<<(NBUCK * 64 + 511) / 512, 512, 0, stream>>>(histT, btot);
    scanB<<<1, 1024, 0, stream>>>(btot, bptr);
    bscatter2<<<NBLK, 1024, 0, stream>>>(vals, row, col, histT, bptr, grouped4, rlb);
    bucket_sort<<<NBUCK, 512, 0, stream>>>(bptr, grouped4, rlb, csr, row_ptr);
    fix_tail<<<1, 1, 0, stream>>>(row_ptr);

    // concat tables -> bf16
    to_bf16<<<2048, 256, 0, stream>>>((const float4*)user_table,
                                      (const float4*)item_table, (ushort4*)xbf);

    // hop 0
    init_acc<<<(BATCH * EMBED_DIM) / 256, 256, 0, stream>>>(user_table, item_table,
                                                            users, items, uacc, iacc);
    // hop 1 (full N)
    spmm_pull<<<(NNODE + 3) / 4, 256, 0, stream>>>(row_ptr, csr, xbf, bufA);
    gather_add<<<(BATCH * EMBED_DIM) / 256, 256, 0, stream>>>(bufA, users, items, uacc, iacc);
    // hop 2 (full N); output aliases `grouped4` (dead after bucket_sort)
    unsigned short* bufB = (unsigned short*)grouped4;
    spmm_pull<<<(NNODE + 3) / 4, 256, 0, stream>>>(row_ptr, csr, bufA, bufB);
    gather_add<<<(BATCH * EMBED_DIM) / 256, 256, 0, stream>>>(bufB, users, items, uacc, iacc);
    // hop 3 (restricted to the 8192 batch rows)
    batch_pull<<<(2 * BATCH * 64) / 256, 256, 0, stream>>>(row_ptr, csr, bufB,
                                                           users, items, uacc, iacc);
    // scores
    score_kernel<<<(BATCH * EMBED_DIM) / 256, 256, 0, stream>>>(uacc, iacc, out);
}

// Round 16
// 285.914 us; speedup vs baseline: 1.1826x; 1.1826x over previous
//
#include <hip/hip_runtime.h>

#define NUM_USER 100000
#define NUM_ITEM 50000
#define NNODE 150000
#define EMBED_DIM 64
#define NNZ_CNT 5000000
#define BATCH 4096

#define BROWS 256
#define NBUCK ((NNODE + BROWS - 1) / BROWS)       // 586
#define NBLK 512
#define CHUNK4 9768                                // per-block edges, multiple of 8
#define COLMASK 0x3FFFF                            // 18 bits, col < 262144
#define RLSHIFT 18                                 // rl in bits 18..25 of grouped.x
#define VSHIFT 18                                  // val14 in bits 18..31 of packed csr
#define VSCALE (1.0f / 16384.0f)

__device__ __forceinline__ unsigned short f2bf(float f) {
    unsigned b = __float_as_uint(f);
    return (unsigned short)((b + 0x7FFFu + ((b >> 16) & 1u)) >> 16);  // RNE
}
__device__ __forceinline__ float bf2f(unsigned short u) {
    return __uint_as_float((unsigned)u << 16);
}

// ---------- CSR build: per-block hist -> 2-level scan -> scatter -> bucket sort ----------
// (r13-proven build: int2 grouped record, single 8B scatter per edge.)

__global__ __launch_bounds__(1024) void bhist_local(const int* __restrict__ row,
                                                    int* __restrict__ histT) {
    __shared__ int lh[NBUCK];
    for (int i = threadIdx.x; i < NBUCK; i += blockDim.x) lh[i] = 0;
    __syncthreads();
    const int lo = blockIdx.x * CHUNK4;
    const int hi = min(lo + CHUNK4, NNZ_CNT);
    for (int base = lo; base < hi; base += 4096) {
        const int e0 = base + (int)threadIdx.x * 4;
        if (e0 + 4 <= hi) {
            const int4 r4 = *(const int4*)&row[e0];
            atomicAdd(&lh[r4.x >> 8], 1);
            atomicAdd(&lh[r4.y >> 8], 1);
            atomicAdd(&lh[r4.z >> 8], 1);
            atomicAdd(&lh[r4.w >> 8], 1);
        } else if (e0 < hi) {
            for (int e = e0; e < hi; ++e) atomicAdd(&lh[row[e] >> 8], 1);
        }
    }
    __syncthreads();
    for (int i = threadIdx.x; i < NBUCK; i += blockDim.x)
        histT[i * NBLK + blockIdx.x] = lh[i];
}

__global__ __launch_bounds__(512) void scanA(int* __restrict__ histT,
                                             int* __restrict__ btot) {
    const int g = (int)((blockIdx.x * blockDim.x + threadIdx.x) >> 6);
    const int lane = threadIdx.x & 63;
    if (g >= NBUCK) return;
    const int base = g * NBLK + lane * 8;
    int v[8];
    int s = 0;
    #pragma unroll
    for (int u = 0; u < 8; ++u) { v[u] = histT[base + u]; s += v[u]; }
    int pre = s;
    #pragma unroll
    for (int off = 1; off < 64; off <<= 1) {
        int t = __shfl_up(pre, off, 64);
        if (lane >= off) pre += t;
    }
    int excl = pre - s;
    #pragma unroll
    for (int u = 0; u < 8; ++u) { const int w = v[u]; histT[base + u] = excl; excl += w; }
    if (lane == 63) btot[g] = pre;
}

__global__ __launch_bounds__(1024) void scanB(const int* __restrict__ btot,
                                              int* __restrict__ bptr) {
    __shared__ int sums[1024];
    const int t = threadIdx.x;
    const int s = (t < NBUCK) ? btot[t] : 0;
    sums[t] = s;
    __syncthreads();
    for (int off = 1; off < 1024; off <<= 1) {
        int v = (t >= off) ? sums[t - off] : 0;
        __syncthreads();
        sums[t] += v;
        __syncthreads();
    }
    if (t < NBUCK) bptr[t] = sums[t] - s;
    if (t == 0) bptr[NBUCK] = NNZ_CNT;
}

__global__ __launch_bounds__(1024) void bscatter2(const float* __restrict__ vals,
                                                  const int* __restrict__ row,
                                                  const int* __restrict__ col,
                                                  const int* __restrict__ histT,
                                                  const int* __restrict__ bptr,
                                                  int2* __restrict__ grouped) {
    __shared__ int lh[NBUCK];
    const int b = blockIdx.x;
    for (int i = threadIdx.x; i < NBUCK; i += blockDim.x)
        lh[i] = bptr[i] + histT[i * NBLK + b];
    __syncthreads();
    const int lo = b * CHUNK4;
    const int hi = min(lo + CHUNK4, NNZ_CNT);
    for (int base = lo; base < hi; base += 4096) {
        const int e0 = base + (int)threadIdx.x * 4;
        if (e0 + 4 <= hi) {
            const int4   r4 = *(const int4*)&row[e0];
            const int4   c4 = *(const int4*)&col[e0];
            const float4 v4 = *(const float4*)&vals[e0];
            const int p0 = atomicAdd(&lh[r4.x >> 8], 1);
            const int p1 = atomicAdd(&lh[r4.y >> 8], 1);
            const int p2 = atomicAdd(&lh[r4.z >> 8], 1);
            const int p3 = atomicAdd(&lh[r4.w >> 8], 1);
            grouped[p0] = make_int2(c4.x | ((r4.x & 255) << RLSHIFT), __float_as_int(v4.x));
            grouped[p1] = make_int2(c4.y | ((r4.y & 255) << RLSHIFT), __float_as_int(v4.y));
            grouped[p2] = make_int2(c4.z | ((r4.z & 255) << RLSHIFT), __float_as_int(v4.z));
            grouped[p3] = make_int2(c4.w | ((r4.w & 255) << RLSHIFT), __float_as_int(v4.w));
        } else if (e0 < hi) {
            for (int e = e0; e < hi; ++e) {
                const int r = row[e];
                const int pos = atomicAdd(&lh[r >> 8], 1);
                grouped[pos] = make_int2(col[e] | ((r & 255) << RLSHIFT), __float_as_int(vals[e]));
            }
        }
    }
}

__global__ __launch_bounds__(512) void bucket_sort(const int* __restrict__ bptr,
                                                   const int2* __restrict__ grouped,
                                                   unsigned* __restrict__ csr,
                                                   int* __restrict__ row_ptr) {
    __shared__ int lh[BROWS];
    __shared__ int lbase[BROWS];
    const int b = blockIdx.x;
    const int bstart = bptr[b];
    const int bend   = bptr[b + 1];
    if (threadIdx.x < BROWS) lh[threadIdx.x] = 0;
    __syncthreads();
    int e = bstart + (int)threadIdx.x;
    for (; e + 1536 < bend; e += 2048) {
        const unsigned x0 = (unsigned)grouped[e].x;
        const unsigned x1 = (unsigned)grouped[e + 512].x;
        const unsigned x2 = (unsigned)grouped[e + 1024].x;
        const unsigned x3 = (unsigned)grouped[e + 1536].x;
        atomicAdd(&lh[x0 >> RLSHIFT], 1);
        atomicAdd(&lh[x1 >> RLSHIFT], 1);
        atomicAdd(&lh[x2 >> RLSHIFT], 1);
        atomicAdd(&lh[x3 >> RLSHIFT], 1);
    }
    for (; e < bend; e += 512)
        atomicAdd(&lh[((unsigned)grouped[e].x) >> RLSHIFT], 1);
    __syncthreads();
    if (threadIdx.x == 0) {
        int run = 0;
        for (int i = 0; i < BROWS; ++i) { const int c = lh[i]; lbase[i] = run; run += c; }
    }
    __syncthreads();
    const int node = b * BROWS + (int)threadIdx.x;
    if (threadIdx.x < BROWS && node < NNODE) row_ptr[node] = bstart + lbase[threadIdx.x];
    if (threadIdx.x < BROWS) lh[threadIdx.x] = lbase[threadIdx.x];
    __syncthreads();
    auto emit = [&](int2 rec) {
        const int rl = ((unsigned)rec.x) >> RLSHIFT;
        const int pos = bstart + atomicAdd(&lh[rl], 1);
        unsigned u = (unsigned)(__int_as_float(rec.y) * 16384.0f + 0.5f);
        if (u > 16383u) u = 16383u;
        csr[pos] = (u << VSHIFT) | ((unsigned)rec.x & COLMASK);
    };
    e = bstart + (int)threadIdx.x;
    for (; e + 1536 < bend; e += 2048) {
        const int2 r0 = grouped[e];
        const int2 r1 = grouped[e + 512];
        const int2 r2 = grouped[e + 1024];
        const int2 r3 = grouped[e + 1536];
        emit(r0); emit(r1); emit(r2); emit(r3);
    }
    for (; e < bend; e += 512) emit(grouped[e]);
}

__global__ void fix_tail(int* __restrict__ row_ptr) {
    row_ptr[NNODE] = NNZ_CNT;
}

// ---------- table concat -> bf16 ----------

__global__ void to_bf16(const float4* __restrict__ ut, const float4* __restrict__ it,
                        ushort4* __restrict__ xbf) {
    const int nu4 = NUM_USER * EMBED_DIM / 4;
    const int nt4 = NNODE * EMBED_DIM / 4;
    int i = blockIdx.x * blockDim.x + threadIdx.x;
    const int stride = gridDim.x * blockDim.x;
    for (; i < nt4; i += stride) {
        const float4 v = (i < nu4) ? ut[i] : it[i - nu4];
        ushort4 o;
        o.x = f2bf(v.x); o.y = f2bf(v.y); o.z = f2bf(v.z); o.w = f2bf(v.w);
        xbf[i] = o;
    }
}

// ---------- pull-mode SpMM (bf16 in / bf16 out), packed 4B CSR ----------
// r13-proven form with one tweak: gather index in 32-bit unsigned arithmetic
// ((col<<6)|lane < 2^24) so the compiler can use saddr + 32-bit voffset
// addressing instead of 64-bit per-lane add chains.

__global__ __launch_bounds__(256) void spmm_pull(const int* __restrict__ row_ptr,
                          const unsigned* __restrict__ csr,
                          const unsigned short* __restrict__ x,
                          unsigned short* __restrict__ y) {
    const int wave = (int)((blockIdx.x * blockDim.x + threadIdx.x) >> 6);
    const unsigned lane = threadIdx.x & 63;
    if (wave >= NNODE) return;
    const int start = __builtin_amdgcn_readfirstlane(row_ptr[wave]);
    const int end   = __builtin_amdgcn_readfirstlane(row_ptr[wave + 1]);
    float acc = 0.f;
    int j = start;
    for (; j + 16 <= end; j += 16) {
        unsigned ee[16]; float xv[16];
        #pragma unroll
        for (int u = 0; u < 16; ++u) {
            __builtin_memcpy(&ee[u], &csr[j + u], 4);            // s_load, const offset
            xv[u] = bf2f(x[((ee[u] & COLMASK) << 6) | lane]);    // 32-bit voffset
        }
        #pragma unroll
        for (int u = 0; u < 16; ++u) acc += (float)(ee[u] >> VSHIFT) * xv[u];
    }
    const int rem = end - j;
    if (rem > 8) {                                 // masked-16 (wave-uniform branch)
        float vv[16], xv[16];
        #pragma unroll
        for (int u = 0; u < 16; ++u) {
            const int jj = j + u;
            const int idx = (jj < end) ? jj : end - 1;
            unsigned e; __builtin_memcpy(&e, &csr[idx], 4);
            vv[u] = (jj < end) ? (float)(e >> VSHIFT) : 0.f;
            xv[u] = bf2f(x[((e & COLMASK) << 6) | lane]);
        }
        #pragma unroll
        for (int u = 0; u < 16; ++u) acc += vv[u] * xv[u];
    } else if (rem > 0) {                          // masked-8
        float vv[8], xv[8];
        #pragma unroll
        for (int u = 0; u < 8; ++u) {
            const int jj = j + u;
            const int idx = (jj < end) ? jj : end - 1;
            unsigned e; __builtin_memcpy(&e, &csr[idx], 4);
            vv[u] = (jj < end) ? (float)(e >> VSHIFT) : 0.f;
            xv[u] = bf2f(x[((e & COLMASK) << 6) | lane]);
        }
        #pragma unroll
        for (int u = 0; u < 8; ++u) acc += vv[u] * xv[u];
    }
    y[(size_t)wave * EMBED_DIM + lane] = f2bf(acc * VSCALE);
}

// Layer-3 restricted pull for the 8192 batch rows only (same pattern).
__global__ __launch_bounds__(256) void batch_pull(const int* __restrict__ row_ptr,
                           const unsigned* __restrict__ csr,
                           const unsigned short* __restrict__ x,
                           const int* __restrict__ users,
                           const int* __restrict__ items,
                           float* __restrict__ uacc,
                           float* __restrict__ iacc) {
    const int g = (int)((blockIdx.x * blockDim.x + threadIdx.x) >> 6);
    const unsigned lane = threadIdx.x & 63;
    if (g >= 2 * BATCH) return;
    const bool is_item = g >= BATCH;
    const int b = is_item ? g - BATCH : g;
    const int node = is_item ? items[b] + NUM_USER : users[b];
    const int start = __builtin_amdgcn_readfirstlane(row_ptr[node]);
    const int end   = __builtin_amdgcn_readfirstlane(row_ptr[node + 1]);
    float acc = 0.f;
    int j = start;
    for (; j + 16 <= end; j += 16) {
        unsigned ee[16]; float xv[16];
        #pragma unroll
        for (int u = 0; u < 16; ++u) {
            __builtin_memcpy(&ee[u], &csr[j + u], 4);
            xv[u] = bf2f(x[((ee[u] & COLMASK) << 6) | lane]);
        }
        #pragma unroll
        for (int u = 0; u < 16; ++u) acc += (float)(ee[u] >> VSHIFT) * xv[u];
    }
    const int rem = end - j;
    if (rem > 8) {
        float vv[16], xv[16];
        #pragma unroll
        for (int u = 0; u < 16; ++u) {
            const int jj = j + u;
            const int idx = (jj < end) ? jj : end - 1;
            unsigned e; __builtin_memcpy(&e, &csr[idx], 4);
            vv[u] = (jj < end) ? (float)(e >> VSHIFT) : 0.f;
            xv[u] = bf2f(x[((e & COLMASK) << 6) | lane]);
        }
        #pragma unroll
        for (int u = 0; u < 16; ++u) acc += vv[u] * xv[u];
    } else if (rem > 0) {
        float vv[8], xv[8];
        #pragma unroll
        for (int u = 0; u < 8; ++u) {
            const int jj = j + u;
            const int idx = (jj < end) ? jj : end - 1;
            unsigned e; __builtin_memcpy(&e, &csr[idx], 4);
            vv[u] = (jj < end) ? (float)(e >> VSHIFT) : 0.f;
            xv[u] = bf2f(x[((e & COLMASK) << 6) | lane]);
        }
        #pragma unroll
        for (int u = 0; u < 8; ++u) acc += vv[u] * xv[u];
    }
    float* dst = is_item ? iacc : uacc;
    dst[(size_t)b * EMBED_DIM + lane] += acc * VSCALE;
}

// ---------- accumulators / scoring ----------

__global__ void init_acc(const float* __restrict__ user_table,
                         const float* __restrict__ item_table,
                         const int* __restrict__ users,
                         const int* __restrict__ items,
                         float* __restrict__ uacc,
                         float* __restrict__ iacc) {
    const int tid = blockIdx.x * blockDim.x + threadIdx.x;
    const int b = tid >> 6;
    const int k = tid & 63;
    uacc[tid] = user_table[(size_t)users[b] * EMBED_DIM + k];
    iacc[tid] = item_table[(size_t)items[b] * EMBED_DIM + k];
}

__global__ void gather_add(const unsigned short* __restrict__ src,
                           const int* __restrict__ users,
                           const int* __restrict__ items,
                           float* __restrict__ uacc,
                           float* __restrict__ iacc) {
    const int tid = blockIdx.x * blockDim.x + threadIdx.x;
    const int b = tid >> 6;
    const int k = tid & 63;
    uacc[tid] += bf2f(src[(size_t)users[b] * EMBED_DIM + k]);
    iacc[tid] += bf2f(src[((size_t)items[b] + NUM_USER) * EMBED_DIM + k]);
}

__global__ void score_kernel(const float* __restrict__ uacc,
                             const float* __restrict__ iacc,
                             float* __restrict__ out) {
    const int tid = blockIdx.x * blockDim.x + threadIdx.x;
    const int b = tid >> 6;
    const int k = tid & 63;
    float p = uacc[tid] * iacc[tid];
    #pragma unroll
    for (int off = 32; off > 0; off >>= 1) p += __shfl_down(p, off, 64);
    if (k == 0) out[b] = p * (1.0f / 16.0f);
}

// ---------- launch ----------

extern "C" void kernel_launch(void* const* d_in, const int* in_sizes, int n_in,
                              void* d_out, int out_size, void* d_ws, size_t ws_size,
                              hipStream_t stream) {
    const float* vals       = (const float*)d_in[0];
    const float* user_table = (const float*)d_in[1];
    const float* item_table = (const float*)d_in[2];
    const int*   row        = (const int*)d_in[3];
    const int*   col        = (const int*)d_in[4];
    const int*   users      = (const int*)d_in[5];
    const int*   items      = (const int*)d_in[6];
    float* out = (float*)d_out;

    char* ws = (char*)d_ws;
    size_t off = 0;
    auto alloc = [&](size_t bytes) { char* p = ws + off; off += (bytes + 255) & ~(size_t)255; return p; };
    const size_t NBH = (size_t)NNODE * EMBED_DIM * sizeof(unsigned short); // 19.2 MB
    unsigned short* xbf  = (unsigned short*)alloc(NBH);
    unsigned short* bufA = (unsigned short*)alloc(NBH);
    int2*  grouped = (int2*)alloc((size_t)NNZ_CNT * sizeof(int2));      // 40 MB (bufB aliases)
    unsigned* csr  = (unsigned*)alloc((size_t)NNZ_CNT * sizeof(unsigned)); // 20 MB packed
    int*   row_ptr = (int*)alloc((size_t)(NNODE + 1) * sizeof(int));
    int*   bptr    = (int*)alloc((size_t)(NBUCK + 1) * sizeof(int));
    int*   btot    = (int*)alloc((size_t)NBUCK * sizeof(int));
    int*   histT   = (int*)alloc((size_t)NBUCK * NBLK * sizeof(int));   // 1.2 MB
    float* uacc    = (float*)alloc((size_t)BATCH * EMBED_DIM * sizeof(float));
    float* iacc    = (float*)alloc((size_t)BATCH * EMBED_DIM * sizeof(float));

    // CSR build
    bhist_local<<<NBLK, 1024, 0, stream>>>(row, histT);
    scanA<<<(NBUCK * 64 + 511) / 512, 512, 0, stream>>>(histT, btot);
    scanB<<<1, 1024, 0, stream>>>(btot, bptr);
    bscatter2<<<NBLK, 1024, 0, stream>>>(vals, row, col, histT, bptr, grouped);
    bucket_sort<<<NBUCK, 512, 0, stream>>>(bptr, grouped, csr, row_ptr);
    fix_tail<<<1, 1, 0, stream>>>(row_ptr);

    // concat tables -> bf16
    to_bf16<<<2048, 256, 0, stream>>>((const float4*)user_table,
                                      (const float4*)item_table, (ushort4*)xbf);

    // hop 0
    init_acc<<<(BATCH * EMBED_DIM) / 256, 256, 0, stream>>>(user_table, item_table,
                                                            users, items, uacc, iacc);
    // hop 1 (full N)
    spmm_pull<<<(NNODE + 3) / 4, 256, 0, stream>>>(row_ptr, csr, xbf, bufA);
    gather_add<<<(BATCH * EMBED_DIM) / 256, 256, 0, stream>>>(bufA, users, items, uacc, iacc);
    // hop 2 (full N); output aliases `grouped` (dead after bucket_sort)
    unsigned short* bufB = (unsigned short*)grouped;
    spmm_pull<<<(NNODE + 3) / 4, 256, 0, stream>>>(row_ptr, csr, bufA, bufB);
    gather_add<<<(BATCH * EMBED_DIM) / 256, 256, 0, stream>>>(bufB, users, items, uacc, iacc);
    // hop 3 (restricted to the 8192 batch rows)
    batch_pull<<<(2 * BATCH * 64) / 256, 256, 0, stream>>>(row_ptr, csr, bufB,
                                                           users, items, uacc, iacc);
    // scores
    score_kernel<<<(BATCH * EMBED_DIM) / 256, 256, 0, stream>>>(uacc, iacc, out);
}

// Round 17
// 266.211 us; speedup vs baseline: 1.2702x; 1.0740x over previous
//
#include <hip/hip_runtime.h>

#define NUM_USER 100000
#define NUM_ITEM 50000
#define NNODE 150000
#define EMBED_DIM 64
#define NNZ_CNT 5000000
#define BATCH 4096

#define BROWS 256
#define NBUCK ((NNODE + BROWS - 1) / BROWS)       // 586
#define NBLK 512
#define CHUNK4 9768                                // per-block edges, multiple of 8
#define COLMASK 0x3FFFF                            // 18 bits, col < 262144
#define RLSHIFT 18                                 // rl in bits 18..25 of grouped.x
#define VSHIFT 18                                  // val14 in bits 18..31 of packed csr
#define VSCALE (1.0f / 16384.0f)
#define CAP 10240                                  // LDS stage capacity (max bucket ~8900)

__device__ __forceinline__ unsigned short f2bf(float f) {
    unsigned b = __float_as_uint(f);
    return (unsigned short)((b + 0x7FFFu + ((b >> 16) & 1u)) >> 16);  // RNE
}
__device__ __forceinline__ float bf2f(unsigned short u) {
    return __uint_as_float((unsigned)u << 16);
}

// ---------- CSR build: per-block hist -> 2-level scan -> scatter -> bucket sort ----------

__global__ __launch_bounds__(1024) void bhist_local(const int* __restrict__ row,
                                                    int* __restrict__ histT) {
    __shared__ int lh[NBUCK];
    for (int i = threadIdx.x; i < NBUCK; i += blockDim.x) lh[i] = 0;
    __syncthreads();
    const int lo = blockIdx.x * CHUNK4;
    const int hi = min(lo + CHUNK4, NNZ_CNT);
    for (int base = lo; base < hi; base += 4096) {
        const int e0 = base + (int)threadIdx.x * 4;
        if (e0 + 4 <= hi) {
            const int4 r4 = *(const int4*)&row[e0];
            atomicAdd(&lh[r4.x >> 8], 1);
            atomicAdd(&lh[r4.y >> 8], 1);
            atomicAdd(&lh[r4.z >> 8], 1);
            atomicAdd(&lh[r4.w >> 8], 1);
        } else if (e0 < hi) {
            for (int e = e0; e < hi; ++e) atomicAdd(&lh[row[e] >> 8], 1);
        }
    }
    __syncthreads();
    for (int i = threadIdx.x; i < NBUCK; i += blockDim.x)
        histT[i * NBLK + blockIdx.x] = lh[i];
}

__global__ __launch_bounds__(512) void scanA(int* __restrict__ histT,
                                             int* __restrict__ btot) {
    const int g = (int)((blockIdx.x * blockDim.x + threadIdx.x) >> 6);
    const int lane = threadIdx.x & 63;
    if (g >= NBUCK) return;
    const int base = g * NBLK + lane * 8;
    int v[8];
    int s = 0;
    #pragma unroll
    for (int u = 0; u < 8; ++u) { v[u] = histT[base + u]; s += v[u]; }
    int pre = s;
    #pragma unroll
    for (int off = 1; off < 64; off <<= 1) {
        int t = __shfl_up(pre, off, 64);
        if (lane >= off) pre += t;
    }
    int excl = pre - s;
    #pragma unroll
    for (int u = 0; u < 8; ++u) { const int w = v[u]; histT[base + u] = excl; excl += w; }
    if (lane == 63) btot[g] = pre;
}

__global__ __launch_bounds__(1024) void scanB(const int* __restrict__ btot,
                                              int* __restrict__ bptr) {
    __shared__ int sums[1024];
    const int t = threadIdx.x;
    const int s = (t < NBUCK) ? btot[t] : 0;
    sums[t] = s;
    __syncthreads();
    for (int off = 1; off < 1024; off <<= 1) {
        int v = (t >= off) ? sums[t - off] : 0;
        __syncthreads();
        sums[t] += v;
        __syncthreads();
    }
    if (t < NBUCK) bptr[t] = sums[t] - s;
    if (t == 0) bptr[NBUCK] = NNZ_CNT;
}

__global__ __launch_bounds__(1024) void bscatter2(const float* __restrict__ vals,
                                                  const int* __restrict__ row,
                                                  const int* __restrict__ col,
                                                  const int* __restrict__ histT,
                                                  const int* __restrict__ bptr,
                                                  int2* __restrict__ grouped) {
    __shared__ int lh[NBUCK];
    const int b = blockIdx.x;
    for (int i = threadIdx.x; i < NBUCK; i += blockDim.x)
        lh[i] = bptr[i] + histT[i * NBLK + b];
    __syncthreads();
    const int lo = b * CHUNK4;
    const int hi = min(lo + CHUNK4, NNZ_CNT);
    for (int base = lo; base < hi; base += 4096) {
        const int e0 = base + (int)threadIdx.x * 4;
        if (e0 + 4 <= hi) {
            const int4   r4 = *(const int4*)&row[e0];
            const int4   c4 = *(const int4*)&col[e0];
            const float4 v4 = *(const float4*)&vals[e0];
            const int p0 = atomicAdd(&lh[r4.x >> 8], 1);
            const int p1 = atomicAdd(&lh[r4.y >> 8], 1);
            const int p2 = atomicAdd(&lh[r4.z >> 8], 1);
            const int p3 = atomicAdd(&lh[r4.w >> 8], 1);
            grouped[p0] = make_int2(c4.x | ((r4.x & 255) << RLSHIFT), __float_as_int(v4.x));
            grouped[p1] = make_int2(c4.y | ((r4.y & 255) << RLSHIFT), __float_as_int(v4.y));
            grouped[p2] = make_int2(c4.z | ((r4.z & 255) << RLSHIFT), __float_as_int(v4.z));
            grouped[p3] = make_int2(c4.w | ((r4.w & 255) << RLSHIFT), __float_as_int(v4.w));
        } else if (e0 < hi) {
            for (int e = e0; e < hi; ++e) {
                const int r = row[e];
                const int pos = atomicAdd(&lh[r >> 8], 1);
                grouped[pos] = make_int2(col[e] | ((r & 255) << RLSHIFT), __float_as_int(vals[e]));
            }
        }
    }
}

// One WG per bucket: hist + scan -> row_ptr; scatter PACKED words into an LDS
// stage at their row-sorted positions; then one linear, fully-coalesced write
// of csr[bstart..bend). Write-amp 3x -> 1x vs scattered 4B global stores.
// Fallback to the scattered path if a bucket exceeds CAP (statistically never).
__global__ __launch_bounds__(512) void bucket_sort(const int* __restrict__ bptr,
                                                   const int2* __restrict__ grouped,
                                                   unsigned* __restrict__ csr,
                                                   int* __restrict__ row_ptr) {
    __shared__ unsigned stage[CAP];          // 40 KB
    __shared__ int lh[BROWS];
    __shared__ int lbase[BROWS];
    const int b = blockIdx.x;
    const int bstart = bptr[b];
    const int bend   = bptr[b + 1];
    const int n = bend - bstart;
    if (threadIdx.x < BROWS) lh[threadIdx.x] = 0;
    __syncthreads();
    int e = bstart + (int)threadIdx.x;
    for (; e + 1536 < bend; e += 2048) {
        const unsigned x0 = (unsigned)grouped[e].x;
        const unsigned x1 = (unsigned)grouped[e + 512].x;
        const unsigned x2 = (unsigned)grouped[e + 1024].x;
        const unsigned x3 = (unsigned)grouped[e + 1536].x;
        atomicAdd(&lh[x0 >> RLSHIFT], 1);
        atomicAdd(&lh[x1 >> RLSHIFT], 1);
        atomicAdd(&lh[x2 >> RLSHIFT], 1);
        atomicAdd(&lh[x3 >> RLSHIFT], 1);
    }
    for (; e < bend; e += 512)
        atomicAdd(&lh[((unsigned)grouped[e].x) >> RLSHIFT], 1);
    __syncthreads();
    if (threadIdx.x == 0) {
        int run = 0;
        for (int i = 0; i < BROWS; ++i) { const int c = lh[i]; lbase[i] = run; run += c; }
    }
    __syncthreads();
    const int node = b * BROWS + (int)threadIdx.x;
    if (threadIdx.x < BROWS && node < NNODE) row_ptr[node] = bstart + lbase[threadIdx.x];
    if (b == 0 && threadIdx.x == 0) row_ptr[NNODE] = NNZ_CNT;   // fix_tail merged
    if (threadIdx.x < BROWS) lh[threadIdx.x] = lbase[threadIdx.x];
    __syncthreads();
    auto pack = [](int2 rec) -> unsigned {
        unsigned u = (unsigned)(__int_as_float(rec.y) * 16384.0f + 0.5f);
        if (u > 16383u) u = 16383u;
        return (u << VSHIFT) | ((unsigned)rec.x & COLMASK);
    };
    if (n <= CAP) {
        // scatter into LDS stage (re-read of grouped is L2-hot), 4-deep ILP
        e = bstart + (int)threadIdx.x;
        for (; e + 1536 < bend; e += 2048) {
            const int2 r0 = grouped[e];
            const int2 r1 = grouped[e + 512];
            const int2 r2 = grouped[e + 1024];
            const int2 r3 = grouped[e + 1536];
            const int p0 = atomicAdd(&lh[((unsigned)r0.x) >> RLSHIFT], 1);
            const int p1 = atomicAdd(&lh[((unsigned)r1.x) >> RLSHIFT], 1);
            const int p2 = atomicAdd(&lh[((unsigned)r2.x) >> RLSHIFT], 1);
            const int p3 = atomicAdd(&lh[((unsigned)r3.x) >> RLSHIFT], 1);
            stage[p0] = pack(r0);
            stage[p1] = pack(r1);
            stage[p2] = pack(r2);
            stage[p3] = pack(r3);
        }
        for (; e < bend; e += 512) {
            const int2 r = grouped[e];
            stage[atomicAdd(&lh[((unsigned)r.x) >> RLSHIFT], 1)] = pack(r);
        }
        __syncthreads();
        // linear, coalesced write-out
        for (int i = threadIdx.x; i < n; i += 512)
            csr[bstart + i] = stage[i];
    } else {
        // fallback: scattered global stores (correct for any bucket size)
        e = bstart + (int)threadIdx.x;
        for (; e < bend; e += 512) {
            const int2 r = grouped[e];
            const int pos = bstart + atomicAdd(&lh[((unsigned)r.x) >> RLSHIFT], 1);
            csr[pos] = pack(r);
        }
    }
}

// ---------- table concat -> bf16 ----------

__global__ void to_bf16(const float4* __restrict__ ut, const float4* __restrict__ it,
                        ushort4* __restrict__ xbf) {
    const int nu4 = NUM_USER * EMBED_DIM / 4;
    const int nt4 = NNODE * EMBED_DIM / 4;
    int i = blockIdx.x * blockDim.x + threadIdx.x;
    const int stride = gridDim.x * blockDim.x;
    for (; i < nt4; i += stride) {
        const float4 v = (i < nu4) ? ut[i] : it[i - nu4];
        ushort4 o;
        o.x = f2bf(v.x); o.y = f2bf(v.y); o.z = f2bf(v.z); o.w = f2bf(v.w);
        xbf[i] = o;
    }
}

// ---------- pull-mode SpMM (bf16 in / bf16 out), packed 4B CSR ----------
// At the L1 miss-line floor (r13/r14/r16 all ~86us): one wave per row,
// wave-uniform scalar CSR loads at constant offsets interleaved with use,
// 32-bit voffset gathers, masked-16/8 wave-uniform tails.

__global__ __launch_bounds__(256) void spmm_pull(const int* __restrict__ row_ptr,
                          const unsigned* __restrict__ csr,
                          const unsigned short* __restrict__ x,
                          unsigned short* __restrict__ y) {
    const int wave = (int)((blockIdx.x * blockDim.x + threadIdx.x) >> 6);
    const unsigned lane = threadIdx.x & 63;
    if (wave >= NNODE) return;
    const int start = __builtin_amdgcn_readfirstlane(row_ptr[wave]);
    const int end   = __builtin_amdgcn_readfirstlane(row_ptr[wave + 1]);
    float acc = 0.f;
    int j = start;
    for (; j + 16 <= end; j += 16) {
        unsigned ee[16]; float xv[16];
        #pragma unroll
        for (int u = 0; u < 16; ++u) {
            __builtin_memcpy(&ee[u], &csr[j + u], 4);            // s_load, const offset
            xv[u] = bf2f(x[((ee[u] & COLMASK) << 6) | lane]);    // 32-bit voffset
        }
        #pragma unroll
        for (int u = 0; u < 16; ++u) acc += (float)(ee[u] >> VSHIFT) * xv[u];
    }
    const int rem = end - j;
    if (rem > 8) {                                 // masked-16 (wave-uniform branch)
        float vv[16], xv[16];
        #pragma unroll
        for (int u = 0; u < 16; ++u) {
            const int jj = j + u;
            const int idx = (jj < end) ? jj : end - 1;
            unsigned e; __builtin_memcpy(&e, &csr[idx], 4);
            vv[u] = (jj < end) ? (float)(e >> VSHIFT) : 0.f;
            xv[u] = bf2f(x[((e & COLMASK) << 6) | lane]);
        }
        #pragma unroll
        for (int u = 0; u < 16; ++u) acc += vv[u] * xv[u];
    } else if (rem > 0) {                          // masked-8
        float vv[8], xv[8];
        #pragma unroll
        for (int u = 0; u < 8; ++u) {
            const int jj = j + u;
            const int idx = (jj < end) ? jj : end - 1;
            unsigned e; __builtin_memcpy(&e, &csr[idx], 4);
            vv[u] = (jj < end) ? (float)(e >> VSHIFT) : 0.f;
            xv[u] = bf2f(x[((e & COLMASK) << 6) | lane]);
        }
        #pragma unroll
        for (int u = 0; u < 8; ++u) acc += vv[u] * xv[u];
    }
    y[(size_t)wave * EMBED_DIM + lane] = f2bf(acc * VSCALE);
}

// Layer-3 restricted pull for the 8192 batch rows only (same pattern).
__global__ __launch_bounds__(256) void batch_pull(const int* __restrict__ row_ptr,
                           const unsigned* __restrict__ csr,
                           const unsigned short* __restrict__ x,
                           const int* __restrict__ users,
                           const int* __restrict__ items,
                           float* __restrict__ uacc,
                           float* __restrict__ iacc) {
    const int g = (int)((blockIdx.x * blockDim.x + threadIdx.x) >> 6);
    const unsigned lane = threadIdx.x & 63;
    if (g >= 2 * BATCH) return;
    const bool is_item = g >= BATCH;
    const int b = is_item ? g - BATCH : g;
    const int node = is_item ? items[b] + NUM_USER : users[b];
    const int start = __builtin_amdgcn_readfirstlane(row_ptr[node]);
    const int end   = __builtin_amdgcn_readfirstlane(row_ptr[node + 1]);
    float acc = 0.f;
    int j = start;
    for (; j + 16 <= end; j += 16) {
        unsigned ee[16]; float xv[16];
        #pragma unroll
        for (int u = 0; u < 16; ++u) {
            __builtin_memcpy(&ee[u], &csr[j + u], 4);
            xv[u] = bf2f(x[((ee[u] & COLMASK) << 6) | lane]);
        }
        #pragma unroll
        for (int u = 0; u < 16; ++u) acc += (float)(ee[u] >> VSHIFT) * xv[u];
    }
    const int rem = end - j;
    if (rem > 8) {
        float vv[16], xv[16];
        #pragma unroll
        for (int u = 0; u < 16; ++u) {
            const int jj = j + u;
            const int idx = (jj < end) ? jj : end - 1;
            unsigned e; __builtin_memcpy(&e, &csr[idx], 4);
            vv[u] = (jj < end) ? (float)(e >> VSHIFT) : 0.f;
            xv[u] = bf2f(x[((e & COLMASK) << 6) | lane]);
        }
        #pragma unroll
        for (int u = 0; u < 16; ++u) acc += vv[u] * xv[u];
    } else if (rem > 0) {
        float vv[8], xv[8];
        #pragma unroll
        for (int u = 0; u < 8; ++u) {
            const int jj = j + u;
            const int idx = (jj < end) ? jj : end - 1;
            unsigned e; __builtin_memcpy(&e, &csr[idx], 4);
            vv[u] = (jj < end) ? (float)(e >> VSHIFT) : 0.f;
            xv[u] = bf2f(x[((e & COLMASK) << 6) | lane]);
        }
        #pragma unroll
        for (int u = 0; u < 8; ++u) acc += vv[u] * xv[u];
    }
    float* dst = is_item ? iacc : uacc;
    dst[(size_t)b * EMBED_DIM + lane] += acc * VSCALE;
}

// ---------- accumulators / scoring ----------

__global__ void init_acc(const float* __restrict__ user_table,
                         const float* __restrict__ item_table,
                         const int* __restrict__ users,
                         const int* __restrict__ items,
                         float* __restrict__ uacc,
                         float* __restrict__ iacc) {
    const int tid = blockIdx.x * blockDim.x + threadIdx.x;
    const int b = tid >> 6;
    const int k = tid & 63;
    uacc[tid] = user_table[(size_t)users[b] * EMBED_DIM + k];
    iacc[tid] = item_table[(size_t)items[b] * EMBED_DIM + k];
}

__global__ void gather_add(const unsigned short* __restrict__ src,
                           const int* __restrict__ users,
                           const int* __restrict__ items,
                           float* __restrict__ uacc,
                           float* __restrict__ iacc) {
    const int tid = blockIdx.x * blockDim.x + threadIdx.x;
    const int b = tid >> 6;
    const int k = tid & 63;
    uacc[tid] += bf2f(src[(size_t)users[b] * EMBED_DIM + k]);
    iacc[tid] += bf2f(src[((size_t)items[b] + NUM_USER) * EMBED_DIM + k]);
}

__global__ void score_kernel(const float* __restrict__ uacc,
                             const float* __restrict__ iacc,
                             float* __restrict__ out) {
    const int tid = blockIdx.x * blockDim.x + threadIdx.x;
    const int b = tid >> 6;
    const int k = tid & 63;
    float p = uacc[tid] * iacc[tid];
    #pragma unroll
    for (int off = 32; off > 0; off >>= 1) p += __shfl_down(p, off, 64);
    if (k == 0) out[b] = p * (1.0f / 16.0f);
}

// ---------- launch ----------

extern "C" void kernel_launch(void* const* d_in, const int* in_sizes, int n_in,
                              void* d_out, int out_size, void* d_ws, size_t ws_size,
                              hipStream_t stream) {
    const float* vals       = (const float*)d_in[0];
    const float* user_table = (const float*)d_in[1];
    const float* item_table = (const float*)d_in[2];
    const int*   row        = (const int*)d_in[3];
    const int*   col        = (const int*)d_in[4];
    const int*   users      = (const int*)d_in[5];
    const int*   items      = (const int*)d_in[6];
    float* out = (float*)d_out;

    char* ws = (char*)d_ws;
    size_t off = 0;
    auto alloc = [&](size_t bytes) { char* p = ws + off; off += (bytes + 255) & ~(size_t)255; return p; };
    const size_t NBH = (size_t)NNODE * EMBED_DIM * sizeof(unsigned short); // 19.2 MB
    unsigned short* xbf  = (unsigned short*)alloc(NBH);
    unsigned short* bufA = (unsigned short*)alloc(NBH);
    int2*  grouped = (int2*)alloc((size_t)NNZ_CNT * sizeof(int2));      // 40 MB (bufB aliases)
    unsigned* csr  = (unsigned*)alloc((size_t)NNZ_CNT * sizeof(unsigned)); // 20 MB packed
    int*   row_ptr = (int*)alloc((size_t)(NNODE + 1) * sizeof(int));
    int*   bptr    = (int*)alloc((size_t)(NBUCK + 1) * sizeof(int));
    int*   btot    = (int*)alloc((size_t)NBUCK * sizeof(int));
    int*   histT   = (int*)alloc((size_t)NBUCK * NBLK * sizeof(int));   // 1.2 MB
    float* uacc    = (float*)alloc((size_t)BATCH * EMBED_DIM * sizeof(float));
    float* iacc    = (float*)alloc((size_t)BATCH * EMBED_DIM * sizeof(float));

    // CSR build
    bhist_local<<<NBLK, 1024, 0, stream>>>(row, histT);
    scanA<<<(NBUCK * 64 + 511) / 512, 512, 0, stream>>>(histT, btot);
    scanB<<<1, 1024, 0, stream>>>(btot, bptr);
    bscatter2<<<NBLK, 1024, 0, stream>>>(vals, row, col, histT, bptr, grouped);
    bucket_sort<<<NBUCK, 512, 0, stream>>>(bptr, grouped, csr, row_ptr);

    // concat tables -> bf16
    to_bf16<<<2048, 256, 0, stream>>>((const float4*)user_table,
                                      (const float4*)item_table, (ushort4*)xbf);

    // hop 0
    init_acc<<<(BATCH * EMBED_DIM) / 256, 256, 0, stream>>>(user_table, item_table,
                                                            users, items, uacc, iacc);
    // hop 1 (full N)
    spmm_pull<<<(NNODE + 3) / 4, 256, 0, stream>>>(row_ptr, csr, xbf, bufA);
    gather_add<<<(BATCH * EMBED_DIM) / 256, 256, 0, stream>>>(bufA, users, items, uacc, iacc);
    // hop 2 (full N); output aliases `grouped` (dead after bucket_sort)
    unsigned short* bufB = (unsigned short*)grouped;
    spmm_pull<<<(NNODE + 3) / 4, 256, 0, stream>>>(row_ptr, csr, bufA, bufB);
    gather_add<<<(BATCH * EMBED_DIM) / 256, 256, 0, stream>>>(bufB, users, items, uacc, iacc);
    // hop 3 (restricted to the 8192 batch rows)
    batch_pull<<<(2 * BATCH * 64) / 256, 256, 0, stream>>>(row_ptr, csr, bufB,
                                                           users, items, uacc, iacc);
    // scores
    score_kernel<<<(BATCH * EMBED_DIM) / 256, 256, 0, stream>>>(uacc, iacc, out);
}

// Round 18
// 262.355 us; speedup vs baseline: 1.2888x; 1.0147x over previous
//
#include <hip/hip_runtime.h>

#define NUM_USER 100000
#define NUM_ITEM 50000
#define NNODE 150000
#define EMBED_DIM 64
#define NNZ_CNT 5000000
#define BATCH 4096

#define BROWS 256
#define NBUCK ((NNODE + BROWS - 1) / BROWS)       // 586
#define NBLK 512
#define CHUNK4 9768                                // per-block edges, multiple of 8
#define COLMASK 0x3FFFF                            // 18 bits, col < 262144
#define RLSHIFT 18                                 // rl in bits 18..25 of grouped.x
#define VSHIFT 18                                  // val14 in bits 18..31 of packed csr
#define VSCALE (1.0f / 16384.0f)
#define CAP 10240                                  // LDS stage capacity (max bucket ~8900)

__device__ __forceinline__ unsigned short f2bf(float f) {
    unsigned b = __float_as_uint(f);
    return (unsigned short)((b + 0x7FFFu + ((b >> 16) & 1u)) >> 16);  // RNE
}
__device__ __forceinline__ float bf2f(unsigned short u) {
    return __uint_as_float((unsigned)u << 16);
}

// ---------- CSR build: per-block hist -> 2-level scan -> scatter -> bucket sort ----------

// Per-block LDS histogram; 8 consecutive edges/thread (2x int4 loads, 8-deep ILP).
__global__ __launch_bounds__(1024) void bhist_local(const int* __restrict__ row,
                                                    int* __restrict__ histT) {
    __shared__ int lh[NBUCK];
    for (int i = threadIdx.x; i < NBUCK; i += blockDim.x) lh[i] = 0;
    __syncthreads();
    const int lo = blockIdx.x * CHUNK4;
    const int hi = min(lo + CHUNK4, NNZ_CNT);
    for (int base = lo; base < hi; base += 8192) {
        const int e0 = base + (int)threadIdx.x * 8;
        if (e0 + 8 <= hi) {
            const int4 ra = *(const int4*)&row[e0];
            const int4 rb = *(const int4*)&row[e0 + 4];
            atomicAdd(&lh[ra.x >> 8], 1);
            atomicAdd(&lh[ra.y >> 8], 1);
            atomicAdd(&lh[ra.z >> 8], 1);
            atomicAdd(&lh[ra.w >> 8], 1);
            atomicAdd(&lh[rb.x >> 8], 1);
            atomicAdd(&lh[rb.y >> 8], 1);
            atomicAdd(&lh[rb.z >> 8], 1);
            atomicAdd(&lh[rb.w >> 8], 1);
        } else if (e0 < hi) {
            for (int e = e0; e < hi; ++e) atomicAdd(&lh[row[e] >> 8], 1);
        }
    }
    __syncthreads();
    for (int i = threadIdx.x; i < NBUCK; i += blockDim.x)
        histT[i * NBLK + blockIdx.x] = lh[i];
}

__global__ __launch_bounds__(512) void scanA(int* __restrict__ histT,
                                             int* __restrict__ btot) {
    const int g = (int)((blockIdx.x * blockDim.x + threadIdx.x) >> 6);
    const int lane = threadIdx.x & 63;
    if (g >= NBUCK) return;
    const int base = g * NBLK + lane * 8;
    int v[8];
    int s = 0;
    #pragma unroll
    for (int u = 0; u < 8; ++u) { v[u] = histT[base + u]; s += v[u]; }
    int pre = s;
    #pragma unroll
    for (int off = 1; off < 64; off <<= 1) {
        int t = __shfl_up(pre, off, 64);
        if (lane >= off) pre += t;
    }
    int excl = pre - s;
    #pragma unroll
    for (int u = 0; u < 8; ++u) { const int w = v[u]; histT[base + u] = excl; excl += w; }
    if (lane == 63) btot[g] = pre;
}

__global__ __launch_bounds__(1024) void scanB(const int* __restrict__ btot,
                                              int* __restrict__ bptr) {
    __shared__ int sums[1024];
    const int t = threadIdx.x;
    const int s = (t < NBUCK) ? btot[t] : 0;
    sums[t] = s;
    __syncthreads();
    for (int off = 1; off < 1024; off <<= 1) {
        int v = (t >= off) ? sums[t - off] : 0;
        __syncthreads();
        sums[t] += v;
        __syncthreads();
    }
    if (t < NBUCK) bptr[t] = sums[t] - s;
    if (t == 0) bptr[NBUCK] = NNZ_CNT;
}

// Scatter edges into bucket-grouped order; 8 consecutive edges/thread (8-deep ILP).
__global__ __launch_bounds__(1024) void bscatter2(const float* __restrict__ vals,
                                                  const int* __restrict__ row,
                                                  const int* __restrict__ col,
                                                  const int* __restrict__ histT,
                                                  const int* __restrict__ bptr,
                                                  int2* __restrict__ grouped) {
    __shared__ int lh[NBUCK];
    const int b = blockIdx.x;
    for (int i = threadIdx.x; i < NBUCK; i += blockDim.x)
        lh[i] = bptr[i] + histT[i * NBLK + b];
    __syncthreads();
    const int lo = b * CHUNK4;
    const int hi = min(lo + CHUNK4, NNZ_CNT);
    for (int base = lo; base < hi; base += 8192) {
        const int e0 = base + (int)threadIdx.x * 8;
        if (e0 + 8 <= hi) {
            const int4   ra = *(const int4*)&row[e0];
            const int4   rb = *(const int4*)&row[e0 + 4];
            const int4   ca = *(const int4*)&col[e0];
            const int4   cb = *(const int4*)&col[e0 + 4];
            const float4 va = *(const float4*)&vals[e0];
            const float4 vb = *(const float4*)&vals[e0 + 4];
            const int p0 = atomicAdd(&lh[ra.x >> 8], 1);
            const int p1 = atomicAdd(&lh[ra.y >> 8], 1);
            const int p2 = atomicAdd(&lh[ra.z >> 8], 1);
            const int p3 = atomicAdd(&lh[ra.w >> 8], 1);
            const int p4 = atomicAdd(&lh[rb.x >> 8], 1);
            const int p5 = atomicAdd(&lh[rb.y >> 8], 1);
            const int p6 = atomicAdd(&lh[rb.z >> 8], 1);
            const int p7 = atomicAdd(&lh[rb.w >> 8], 1);
            grouped[p0] = make_int2(ca.x | ((ra.x & 255) << RLSHIFT), __float_as_int(va.x));
            grouped[p1] = make_int2(ca.y | ((ra.y & 255) << RLSHIFT), __float_as_int(va.y));
            grouped[p2] = make_int2(ca.z | ((ra.z & 255) << RLSHIFT), __float_as_int(va.z));
            grouped[p3] = make_int2(ca.w | ((ra.w & 255) << RLSHIFT), __float_as_int(va.w));
            grouped[p4] = make_int2(cb.x | ((rb.x & 255) << RLSHIFT), __float_as_int(vb.x));
            grouped[p5] = make_int2(cb.y | ((rb.y & 255) << RLSHIFT), __float_as_int(vb.y));
            grouped[p6] = make_int2(cb.z | ((rb.z & 255) << RLSHIFT), __float_as_int(vb.z));
            grouped[p7] = make_int2(cb.w | ((rb.w & 255) << RLSHIFT), __float_as_int(vb.w));
        } else if (e0 < hi) {
            for (int e = e0; e < hi; ++e) {
                const int r = row[e];
                const int pos = atomicAdd(&lh[r >> 8], 1);
                grouped[pos] = make_int2(col[e] | ((r & 255) << RLSHIFT), __float_as_int(vals[e]));
            }
        }
    }
}

// One WG per bucket: hist + scan -> row_ptr; scatter PACKED words into an LDS
// stage at row-sorted positions; linear coalesced write-out. (r17-proven.)
__global__ __launch_bounds__(512) void bucket_sort(const int* __restrict__ bptr,
                                                   const int2* __restrict__ grouped,
                                                   unsigned* __restrict__ csr,
                                                   int* __restrict__ row_ptr) {
    __shared__ unsigned stage[CAP];          // 40 KB
    __shared__ int lh[BROWS];
    __shared__ int lbase[BROWS];
    const int b = blockIdx.x;
    const int bstart = bptr[b];
    const int bend   = bptr[b + 1];
    const int n = bend - bstart;
    if (threadIdx.x < BROWS) lh[threadIdx.x] = 0;
    __syncthreads();
    int e = bstart + (int)threadIdx.x;
    for (; e + 1536 < bend; e += 2048) {
        const unsigned x0 = (unsigned)grouped[e].x;
        const unsigned x1 = (unsigned)grouped[e + 512].x;
        const unsigned x2 = (unsigned)grouped[e + 1024].x;
        const unsigned x3 = (unsigned)grouped[e + 1536].x;
        atomicAdd(&lh[x0 >> RLSHIFT], 1);
        atomicAdd(&lh[x1 >> RLSHIFT], 1);
        atomicAdd(&lh[x2 >> RLSHIFT], 1);
        atomicAdd(&lh[x3 >> RLSHIFT], 1);
    }
    for (; e < bend; e += 512)
        atomicAdd(&lh[((unsigned)grouped[e].x) >> RLSHIFT], 1);
    __syncthreads();
    if (threadIdx.x == 0) {
        int run = 0;
        for (int i = 0; i < BROWS; ++i) { const int c = lh[i]; lbase[i] = run; run += c; }
    }
    __syncthreads();
    const int node = b * BROWS + (int)threadIdx.x;
    if (threadIdx.x < BROWS && node < NNODE) row_ptr[node] = bstart + lbase[threadIdx.x];
    if (b == 0 && threadIdx.x == 0) row_ptr[NNODE] = NNZ_CNT;
    if (threadIdx.x < BROWS) lh[threadIdx.x] = lbase[threadIdx.x];
    __syncthreads();
    auto pack = [](int2 rec) -> unsigned {
        unsigned u = (unsigned)(__int_as_float(rec.y) * 16384.0f + 0.5f);
        if (u > 16383u) u = 16383u;
        return (u << VSHIFT) | ((unsigned)rec.x & COLMASK);
    };
    if (n <= CAP) {
        e = bstart + (int)threadIdx.x;
        for (; e + 1536 < bend; e += 2048) {
            const int2 r0 = grouped[e];
            const int2 r1 = grouped[e + 512];
            const int2 r2 = grouped[e + 1024];
            const int2 r3 = grouped[e + 1536];
            const int p0 = atomicAdd(&lh[((unsigned)r0.x) >> RLSHIFT], 1);
            const int p1 = atomicAdd(&lh[((unsigned)r1.x) >> RLSHIFT], 1);
            const int p2 = atomicAdd(&lh[((unsigned)r2.x) >> RLSHIFT], 1);
            const int p3 = atomicAdd(&lh[((unsigned)r3.x) >> RLSHIFT], 1);
            stage[p0] = pack(r0);
            stage[p1] = pack(r1);
            stage[p2] = pack(r2);
            stage[p3] = pack(r3);
        }
        for (; e < bend; e += 512) {
            const int2 r = grouped[e];
            stage[atomicAdd(&lh[((unsigned)r.x) >> RLSHIFT], 1)] = pack(r);
        }
        __syncthreads();
        for (int i = threadIdx.x; i < n; i += 512)
            csr[bstart + i] = stage[i];
    } else {
        e = bstart + (int)threadIdx.x;
        for (; e < bend; e += 512) {
            const int2 r = grouped[e];
            const int pos = bstart + atomicAdd(&lh[((unsigned)r.x) >> RLSHIFT], 1);
            csr[pos] = pack(r);
        }
    }
}

// ---------- table concat -> bf16 ----------

__global__ void to_bf16(const float4* __restrict__ ut, const float4* __restrict__ it,
                        ushort4* __restrict__ xbf) {
    const int nu4 = NUM_USER * EMBED_DIM / 4;
    const int nt4 = NNODE * EMBED_DIM / 4;
    int i = blockIdx.x * blockDim.x + threadIdx.x;
    const int stride = gridDim.x * blockDim.x;
    for (; i < nt4; i += stride) {
        const float4 v = (i < nu4) ? ut[i] : it[i - nu4];
        ushort4 o;
        o.x = f2bf(v.x); o.y = f2bf(v.y); o.z = f2bf(v.z); o.w = f2bf(v.w);
        xbf[i] = o;
    }
}

// ---------- pull-mode SpMM (bf16 in / bf16 out), packed 4B CSR ----------
// At the L1 miss-line floor (r13/r14/r16 all ~86us): one wave per row,
// wave-uniform scalar CSR loads at constant offsets interleaved with use,
// 32-bit voffset gathers, masked-16/8 wave-uniform tails.

__global__ __launch_bounds__(256) void spmm_pull(const int* __restrict__ row_ptr,
                          const unsigned* __restrict__ csr,
                          const unsigned short* __restrict__ x,
                          unsigned short* __restrict__ y) {
    const int wave = (int)((blockIdx.x * blockDim.x + threadIdx.x) >> 6);
    const unsigned lane = threadIdx.x & 63;
    if (wave >= NNODE) return;
    const int start = __builtin_amdgcn_readfirstlane(row_ptr[wave]);
    const int end   = __builtin_amdgcn_readfirstlane(row_ptr[wave + 1]);
    float acc = 0.f;
    int j = start;
    for (; j + 16 <= end; j += 16) {
        unsigned ee[16]; float xv[16];
        #pragma unroll
        for (int u = 0; u < 16; ++u) {
            __builtin_memcpy(&ee[u], &csr[j + u], 4);            // s_load, const offset
            xv[u] = bf2f(x[((ee[u] & COLMASK) << 6) | lane]);    // 32-bit voffset
        }
        #pragma unroll
        for (int u = 0; u < 16; ++u) acc += (float)(ee[u] >> VSHIFT) * xv[u];
    }
    const int rem = end - j;
    if (rem > 8) {                                 // masked-16 (wave-uniform branch)
        float vv[16], xv[16];
        #pragma unroll
        for (int u = 0; u < 16; ++u) {
            const int jj = j + u;
            const int idx = (jj < end) ? jj : end - 1;
            unsigned e; __builtin_memcpy(&e, &csr[idx], 4);
            vv[u] = (jj < end) ? (float)(e >> VSHIFT) : 0.f;
            xv[u] = bf2f(x[((e & COLMASK) << 6) | lane]);
        }
        #pragma unroll
        for (int u = 0; u < 16; ++u) acc += vv[u] * xv[u];
    } else if (rem > 0) {                          // masked-8
        float vv[8], xv[8];
        #pragma unroll
        for (int u = 0; u < 8; ++u) {
            const int jj = j + u;
            const int idx = (jj < end) ? jj : end - 1;
            unsigned e; __builtin_memcpy(&e, &csr[idx], 4);
            vv[u] = (jj < end) ? (float)(e >> VSHIFT) : 0.f;
            xv[u] = bf2f(x[((e & COLMASK) << 6) | lane]);
        }
        #pragma unroll
        for (int u = 0; u < 8; ++u) acc += vv[u] * xv[u];
    }
    y[(size_t)wave * EMBED_DIM + lane] = f2bf(acc * VSCALE);
}

// Layer-3 restricted pull for the 8192 batch rows only (same pattern).
__global__ __launch_bounds__(256) void batch_pull(const int* __restrict__ row_ptr,
                           const unsigned* __restrict__ csr,
                           const unsigned short* __restrict__ x,
                           const int* __restrict__ users,
                           const int* __restrict__ items,
                           float* __restrict__ uacc,
                           float* __restrict__ iacc) {
    const int g = (int)((blockIdx.x * blockDim.x + threadIdx.x) >> 6);
    const unsigned lane = threadIdx.x & 63;
    if (g >= 2 * BATCH) return;
    const bool is_item = g >= BATCH;
    const int b = is_item ? g - BATCH : g;
    const int node = is_item ? items[b] + NUM_USER : users[b];
    const int start = __builtin_amdgcn_readfirstlane(row_ptr[node]);
    const int end   = __builtin_amdgcn_readfirstlane(row_ptr[node + 1]);
    float acc = 0.f;
    int j = start;
    for (; j + 16 <= end; j += 16) {
        unsigned ee[16]; float xv[16];
        #pragma unroll
        for (int u = 0; u < 16; ++u) {
            __builtin_memcpy(&ee[u], &csr[j + u], 4);
            xv[u] = bf2f(x[((ee[u] & COLMASK) << 6) | lane]);
        }
        #pragma unroll
        for (int u = 0; u < 16; ++u) acc += (float)(ee[u] >> VSHIFT) * xv[u];
    }
    const int rem = end - j;
    if (rem > 8) {
        float vv[16], xv[16];
        #pragma unroll
        for (int u = 0; u < 16; ++u) {
            const int jj = j + u;
            const int idx = (jj < end) ? jj : end - 1;
            unsigned e; __builtin_memcpy(&e, &csr[idx], 4);
            vv[u] = (jj < end) ? (float)(e >> VSHIFT) : 0.f;
            xv[u] = bf2f(x[((e & COLMASK) << 6) | lane]);
        }
        #pragma unroll
        for (int u = 0; u < 16; ++u) acc += vv[u] * xv[u];
    } else if (rem > 0) {
        float vv[8], xv[8];
        #pragma unroll
        for (int u = 0; u < 8; ++u) {
            const int jj = j + u;
            const int idx = (jj < end) ? jj : end - 1;
            unsigned e; __builtin_memcpy(&e, &csr[idx], 4);
            vv[u] = (jj < end) ? (float)(e >> VSHIFT) : 0.f;
            xv[u] = bf2f(x[((e & COLMASK) << 6) | lane]);
        }
        #pragma unroll
        for (int u = 0; u < 8; ++u) acc += vv[u] * xv[u];
    }
    float* dst = is_item ? iacc : uacc;
    dst[(size_t)b * EMBED_DIM + lane] += acc * VSCALE;
}

// ---------- accumulators / scoring ----------

// hop-0 + hop-1 fused: acc = table[idx] + bf16(hop1[idx])
__global__ void gather_init(const float* __restrict__ user_table,
                            const float* __restrict__ item_table,
                            const unsigned short* __restrict__ src,
                            const int* __restrict__ users,
                            const int* __restrict__ items,
                            float* __restrict__ uacc,
                            float* __restrict__ iacc) {
    const int tid = blockIdx.x * blockDim.x + threadIdx.x;
    const int b = tid >> 6;
    const int k = tid & 63;
    const int u = users[b];
    const int it = items[b];
    uacc[tid] = user_table[(size_t)u * EMBED_DIM + k]
              + bf2f(src[(size_t)u * EMBED_DIM + k]);
    iacc[tid] = item_table[(size_t)it * EMBED_DIM + k]
              + bf2f(src[((size_t)it + NUM_USER) * EMBED_DIM + k]);
}

__global__ void gather_add(const unsigned short* __restrict__ src,
                           const int* __restrict__ users,
                           const int* __restrict__ items,
                           float* __restrict__ uacc,
                           float* __restrict__ iacc) {
    const int tid = blockIdx.x * blockDim.x + threadIdx.x;
    const int b = tid >> 6;
    const int k = tid & 63;
    uacc[tid] += bf2f(src[(size_t)users[b] * EMBED_DIM + k]);
    iacc[tid] += bf2f(src[((size_t)items[b] + NUM_USER) * EMBED_DIM + k]);
}

__global__ void score_kernel(const float* __restrict__ uacc,
                             const float* __restrict__ iacc,
                             float* __restrict__ out) {
    const int tid = blockIdx.x * blockDim.x + threadIdx.x;
    const int b = tid >> 6;
    const int k = tid & 63;
    float p = uacc[tid] * iacc[tid];
    #pragma unroll
    for (int off = 32; off > 0; off >>= 1) p += __shfl_down(p, off, 64);
    if (k == 0) out[b] = p * (1.0f / 16.0f);
}

// ---------- launch ----------

extern "C" void kernel_launch(void* const* d_in, const int* in_sizes, int n_in,
                              void* d_out, int out_size, void* d_ws, size_t ws_size,
                              hipStream_t stream) {
    const float* vals       = (const float*)d_in[0];
    const float* user_table = (const float*)d_in[1];
    const float* item_table = (const float*)d_in[2];
    const int*   row        = (const int*)d_in[3];
    const int*   col        = (const int*)d_in[4];
    const int*   users      = (const int*)d_in[5];
    const int*   items      = (const int*)d_in[6];
    float* out = (float*)d_out;

    char* ws = (char*)d_ws;
    size_t off = 0;
    auto alloc = [&](size_t bytes) { char* p = ws + off; off += (bytes + 255) & ~(size_t)255; return p; };
    const size_t NBH = (size_t)NNODE * EMBED_DIM * sizeof(unsigned short); // 19.2 MB
    unsigned short* xbf  = (unsigned short*)alloc(NBH);
    unsigned short* bufA = (unsigned short*)alloc(NBH);
    int2*  grouped = (int2*)alloc((size_t)NNZ_CNT * sizeof(int2));      // 40 MB (bufB aliases)
    unsigned* csr  = (unsigned*)alloc((size_t)NNZ_CNT * sizeof(unsigned)); // 20 MB packed
    int*   row_ptr = (int*)alloc((size_t)(NNODE + 1) * sizeof(int));
    int*   bptr    = (int*)alloc((size_t)(NBUCK + 1) * sizeof(int));
    int*   btot    = (int*)alloc((size_t)NBUCK * sizeof(int));
    int*   histT   = (int*)alloc((size_t)NBUCK * NBLK * sizeof(int));   // 1.2 MB
    float* uacc    = (float*)alloc((size_t)BATCH * EMBED_DIM * sizeof(float));
    float* iacc    = (float*)alloc((size_t)BATCH * EMBED_DIM * sizeof(float));

    // CSR build
    bhist_local<<<NBLK, 1024, 0, stream>>>(row, histT);
    scanA<<<(NBUCK * 64 + 511) / 512, 512, 0, stream>>>(histT, btot);
    scanB<<<1, 1024, 0, stream>>>(btot, bptr);
    bscatter2<<<NBLK, 1024, 0, stream>>>(vals, row, col, histT, bptr, grouped);
    bucket_sort<<<NBUCK, 512, 0, stream>>>(bptr, grouped, csr, row_ptr);

    // concat tables -> bf16
    to_bf16<<<2048, 256, 0, stream>>>((const float4*)user_table,
                                      (const float4*)item_table, (ushort4*)xbf);

    // hop 1 (full N)
    spmm_pull<<<(NNODE + 3) / 4, 256, 0, stream>>>(row_ptr, csr, xbf, bufA);
    // hop 0 + hop 1 accumulate (fused)
    gather_init<<<(BATCH * EMBED_DIM) / 256, 256, 0, stream>>>(user_table, item_table,
                                                               bufA, users, items, uacc, iacc);
    // hop 2 (full N); output aliases `grouped` (dead after bucket_sort)
    unsigned short* bufB = (unsigned short*)grouped;
    spmm_pull<<<(NNODE + 3) / 4, 256, 0, stream>>>(row_ptr, csr, bufA, bufB);
    gather_add<<<(BATCH * EMBED_DIM) / 256, 256, 0, stream>>>(bufB, users, items, uacc, iacc);
    // hop 3 (restricted to the 8192 batch rows)
    batch_pull<<<(2 * BATCH * 64) / 256, 256, 0, stream>>>(row_ptr, csr, bufB,
                                                           users, items, uacc, iacc);
    // scores
    score_kernel<<<(BATCH * EMBED_DIM) / 256, 256, 0, stream>>>(uacc, iacc, out);
}